// Round 1
// baseline (2077.601 us; speedup 1.0000x reference)
//
#include <hip/hip_runtime.h>

#define N_NODES 50000
#define N_EDGES 1600000
#define FEAT 128
#define HIDDEN 128
#define NUM_CLASS 64

// ---------------- degree computation ----------------
__global__ __launch_bounds__(256) void deg_kernel(const int* __restrict__ ei,
                                                  float* __restrict__ out_deg,
                                                  float* __restrict__ in_deg) {
    int e = blockIdx.x * 256 + threadIdx.x;
    if (e < N_EDGES) {
        atomicAdd(&out_deg[ei[e]], 1.0f);
        atomicAdd(&in_deg[ei[N_EDGES + e]], 1.0f);
    }
}

__global__ __launch_bounds__(256) void isqrt_kernel(float* __restrict__ deg, int n) {
    int i = blockIdx.x * 256 + threadIdx.x;
    if (i < n) {
        float d = deg[i];
        d = d < 1.0f ? 1.0f : d;
        deg[i] = rsqrtf(d);
    }
}

// ---------------- dense projection: Y[n][:] = scale[n] * (H[n][:] @ W) ----------------
template <int OUT>
__global__ __launch_bounds__(256) void gemm_kernel(const float* __restrict__ H,
                                                   const float* __restrict__ W,
                                                   const float* __restrict__ scale,
                                                   float* __restrict__ Y, int n_nodes) {
    constexpr int TN = 32;                    // nodes per block
    __shared__ float Hs[TN][FEAT];            // 16 KB
    __shared__ float Ws[FEAT][OUT];           // 64 KB (OUT=128) / 32 KB (OUT=64)

    const int bn = blockIdx.x * TN;
    const int tid = threadIdx.x;

    for (int i = tid; i < FEAT * OUT; i += 256)
        Ws[i / OUT][i % OUT] = W[i];
    for (int i = tid; i < TN * FEAT; i += 256) {
        int n = bn + i / FEAT;
        Hs[i / FEAT][i % FEAT] = (n < n_nodes) ? H[(long long)n * FEAT + (i % FEAT)] : 0.0f;
    }
    __syncthreads();

    constexpr int CG = OUT / 4;               // float4 column groups per row
    constexpr int NPER = 256 / CG;            // nodes covered per pass
    const int cg = tid % CG;
    const int n0 = tid / CG;

    for (int p = 0; p < TN / NPER; ++p) {
        const int n = n0 + p * NPER;
        float4 acc = {0.f, 0.f, 0.f, 0.f};
#pragma unroll 8
        for (int k = 0; k < FEAT; ++k) {
            const float a = Hs[n][k];
            const float4 w = *(const float4*)&Ws[k][cg * 4];
            acc.x += a * w.x; acc.y += a * w.y; acc.z += a * w.z; acc.w += a * w.w;
        }
        const int gn = bn + n;
        if (gn < n_nodes) {
            const float s = scale[gn];
            float4 r = {acc.x * s, acc.y * s, acc.z * s, acc.w * s};
            *(float4*)&Y[(long long)gn * OUT + cg * 4] = r;
        }
    }
}

// ---------------- edge scatter: agg[dst][f] += Y[src][f] ----------------
template <int F>
__global__ __launch_bounds__(256) void scatter_kernel(const int* __restrict__ ei,
                                                      const float* __restrict__ Y,
                                                      float* __restrict__ agg) {
    const int idx = blockIdx.x * 256 + threadIdx.x;   // < N_EDGES * F (exact grid)
    const int e = idx / F;
    const int f = idx % F;
    const int s = ei[e];
    const int d = ei[N_EDGES + e];
    atomicAdd(&agg[(long long)d * F + f], Y[(long long)s * F + f]);
}

// ---------------- finalize: x = relu(x * in_isqrt[n]) in place ----------------
template <int F>
__global__ __launch_bounds__(256) void finalize_kernel(float* __restrict__ x,
                                                       const float* __restrict__ in_isqrt) {
    const int idx = blockIdx.x * 256 + threadIdx.x;   // < N_NODES * F (exact grid)
    const int n = idx / F;
    float v = x[idx] * in_isqrt[n];
    x[idx] = v > 0.0f ? v : 0.0f;
}

extern "C" void kernel_launch(void* const* d_in, const int* in_sizes, int n_in,
                              void* d_out, int out_size, void* d_ws, size_t ws_size,
                              hipStream_t stream) {
    const float* h  = (const float*)d_in[0];
    const int*   ei = (const int*)d_in[1];
    const float* W1 = (const float*)d_in[2];
    const float* W2 = (const float*)d_in[3];
    const float* W3 = (const float*)d_in[4];
    float* out = (float*)d_out;

    float* out_isqrt = (float*)d_ws;                       // N_NODES
    float* in_isqrt  = out_isqrt + N_NODES;                // N_NODES
    float* buf0      = in_isqrt + N_NODES;                 // N_NODES*HIDDEN (Y)
    float* buf1      = buf0 + (size_t)N_NODES * HIDDEN;    // N_NODES*HIDDEN (agg/h)

    // degrees -> isqrt scales
    hipMemsetAsync(out_isqrt, 0, 2 * N_NODES * sizeof(float), stream);
    deg_kernel<<<(N_EDGES + 255) / 256, 256, 0, stream>>>(ei, out_isqrt, in_isqrt);
    isqrt_kernel<<<(2 * N_NODES + 255) / 256, 256, 0, stream>>>(out_isqrt, 2 * N_NODES);

    const int gemm_blocks = (N_NODES + 31) / 32;

    // ---- layer 1 ----
    gemm_kernel<HIDDEN><<<gemm_blocks, 256, 0, stream>>>(h, W1, out_isqrt, buf0, N_NODES);
    hipMemsetAsync(buf1, 0, (size_t)N_NODES * HIDDEN * sizeof(float), stream);
    scatter_kernel<HIDDEN><<<(int)((long long)N_EDGES * HIDDEN / 256), 256, 0, stream>>>(ei, buf0, buf1);
    finalize_kernel<HIDDEN><<<N_NODES * HIDDEN / 256, 256, 0, stream>>>(buf1, in_isqrt);

    // ---- layer 2 ----
    gemm_kernel<HIDDEN><<<gemm_blocks, 256, 0, stream>>>(buf1, W2, out_isqrt, buf0, N_NODES);
    hipMemsetAsync(buf1, 0, (size_t)N_NODES * HIDDEN * sizeof(float), stream);
    scatter_kernel<HIDDEN><<<(int)((long long)N_EDGES * HIDDEN / 256), 256, 0, stream>>>(ei, buf0, buf1);
    finalize_kernel<HIDDEN><<<N_NODES * HIDDEN / 256, 256, 0, stream>>>(buf1, in_isqrt);

    // ---- layer 3 ----
    gemm_kernel<NUM_CLASS><<<gemm_blocks, 256, 0, stream>>>(buf1, W3, out_isqrt, buf0, N_NODES);
    hipMemsetAsync(out, 0, (size_t)N_NODES * NUM_CLASS * sizeof(float), stream);
    scatter_kernel<NUM_CLASS><<<(int)((long long)N_EDGES * NUM_CLASS / 256), 256, 0, stream>>>(ei, buf0, out);
    finalize_kernel<NUM_CLASS><<<N_NODES * NUM_CLASS / 256, 256, 0, stream>>>(out, in_isqrt);
}

// Round 2
// 741.560 us; speedup vs baseline: 2.8017x; 2.8017x over previous
//
#include <hip/hip_runtime.h>

#define N_NODES 50000
#define N_EDGES 1600000
#define FEAT 128
#define HIDDEN 128
#define NUM_CLASS 64
#define NB_SCAN ((N_NODES + 255) / 256)   // 196 blocks for the scan

// ---------------- histogram: out/in degree counts (int atomics) ----------------
__global__ __launch_bounds__(256) void hist_kernel(const int* __restrict__ ei,
                                                   int* __restrict__ out_cnt,
                                                   int* __restrict__ in_cnt) {
    int e = blockIdx.x * 256 + threadIdx.x;
    if (e < N_EDGES) {
        atomicAdd(&out_cnt[ei[e]], 1);
        atomicAdd(&in_cnt[ei[N_EDGES + e]], 1);
    }
}

// ---------------- isqrt scales from int counts ----------------
__global__ __launch_bounds__(256) void scales_kernel(const int* __restrict__ out_cnt,
                                                     const int* __restrict__ in_cnt,
                                                     float* __restrict__ out_isqrt,
                                                     float* __restrict__ in_isqrt) {
    int i = blockIdx.x * 256 + threadIdx.x;
    if (i < N_NODES) {
        int oc = out_cnt[i]; if (oc < 1) oc = 1;
        int ic = in_cnt[i];  if (ic < 1) ic = 1;
        out_isqrt[i] = 1.0f / sqrtf((float)oc);
        in_isqrt[i]  = 1.0f / sqrtf((float)ic);
    }
}

// ---------------- exclusive scan of in_cnt -> row_offsets (3 kernels) ----------------
__global__ __launch_bounds__(256) void scan1_kernel(const int* __restrict__ in_cnt,
                                                    int* __restrict__ excl,
                                                    int* __restrict__ bsums) {
    __shared__ int tmp[256];
    int i = blockIdx.x * 256 + threadIdx.x;
    int v = (i < N_NODES) ? in_cnt[i] : 0;
    tmp[threadIdx.x] = v;
    __syncthreads();
    for (int off = 1; off < 256; off <<= 1) {
        int t = (threadIdx.x >= off) ? tmp[threadIdx.x - off] : 0;
        __syncthreads();
        tmp[threadIdx.x] += t;
        __syncthreads();
    }
    if (i < N_NODES) excl[i] = tmp[threadIdx.x] - v;     // local exclusive
    if (threadIdx.x == 255) bsums[blockIdx.x] = tmp[255];
}

__global__ __launch_bounds__(256) void scan2_kernel(int* __restrict__ bsums, int nb) {
    __shared__ int tmp[256];
    int v = (threadIdx.x < nb) ? bsums[threadIdx.x] : 0;
    tmp[threadIdx.x] = v;
    __syncthreads();
    for (int off = 1; off < 256; off <<= 1) {
        int t = (threadIdx.x >= off) ? tmp[threadIdx.x - off] : 0;
        __syncthreads();
        tmp[threadIdx.x] += t;
        __syncthreads();
    }
    if (threadIdx.x < nb) bsums[threadIdx.x] = tmp[threadIdx.x] - v;  // exclusive
}

__global__ __launch_bounds__(256) void scan3_kernel(int* __restrict__ row_off,
                                                    const int* __restrict__ bsums,
                                                    int* __restrict__ cursor) {
    int i = blockIdx.x * 256 + threadIdx.x;
    if (i < N_NODES) {
        int v = row_off[i] + bsums[blockIdx.x];
        row_off[i] = v;
        cursor[i] = v;
    }
    if (i == 0) row_off[N_NODES] = N_EDGES;
}

// ---------------- counting-sort placement: csr_src sorted by dst ----------------
__global__ __launch_bounds__(256) void fill_kernel(const int* __restrict__ ei,
                                                   int* __restrict__ cursor,
                                                   int* __restrict__ csr_src) {
    int e = blockIdx.x * 256 + threadIdx.x;
    if (e < N_EDGES) {
        int s = ei[e];
        int d = ei[N_EDGES + e];
        int p = atomicAdd(&cursor[d], 1);
        csr_src[p] = s;
    }
}

// ---------------- dense projection: Y[n][:] = scale[n] * (H[n][:] @ W) ----------------
template <int OUT>
__global__ __launch_bounds__(256) void gemm_kernel(const float* __restrict__ H,
                                                   const float* __restrict__ W,
                                                   const float* __restrict__ scale,
                                                   float* __restrict__ Y, int n_nodes) {
    constexpr int TN = 32;
    __shared__ float Hs[TN][FEAT];
    __shared__ float Ws[FEAT][OUT];

    const int bn = blockIdx.x * TN;
    const int tid = threadIdx.x;

    for (int i = tid; i < FEAT * OUT; i += 256)
        Ws[i / OUT][i % OUT] = W[i];
    for (int i = tid; i < TN * FEAT; i += 256) {
        int n = bn + i / FEAT;
        Hs[i / FEAT][i % FEAT] = (n < n_nodes) ? H[(long long)n * FEAT + (i % FEAT)] : 0.0f;
    }
    __syncthreads();

    constexpr int CG = OUT / 4;
    constexpr int NPER = 256 / CG;
    const int cg = tid % CG;
    const int n0 = tid / CG;

    for (int p = 0; p < TN / NPER; ++p) {
        const int n = n0 + p * NPER;
        float4 acc = {0.f, 0.f, 0.f, 0.f};
#pragma unroll 8
        for (int k = 0; k < FEAT; ++k) {
            const float a = Hs[n][k];
            const float4 w = *(const float4*)&Ws[k][cg * 4];
            acc.x += a * w.x; acc.y += a * w.y; acc.z += a * w.z; acc.w += a * w.w;
        }
        const int gn = bn + n;
        if (gn < n_nodes) {
            const float s = scale[gn];
            float4 r = {acc.x * s, acc.y * s, acc.z * s, acc.w * s};
            *(float4*)&Y[(long long)gn * OUT + cg * 4] = r;
        }
    }
}

// ---------------- CSR gather-aggregate + in_isqrt scale + relu ----------------
template <int F>
__global__ __launch_bounds__(F) void agg_kernel(const int* __restrict__ row_off,
                                                const int* __restrict__ csr_src,
                                                const float* __restrict__ Y,
                                                const float* __restrict__ in_isqrt,
                                                float* __restrict__ out) {
    const int d = blockIdx.x;
    const int f = threadIdx.x;
    const int beg = row_off[d];
    const int end = row_off[d + 1];

    float acc = 0.0f;
    int e = beg;
    for (; e + 4 <= end; e += 4) {
        int s0 = csr_src[e], s1 = csr_src[e + 1], s2 = csr_src[e + 2], s3 = csr_src[e + 3];
        float v0 = Y[(size_t)s0 * F + f];
        float v1 = Y[(size_t)s1 * F + f];
        float v2 = Y[(size_t)s2 * F + f];
        float v3 = Y[(size_t)s3 * F + f];
        acc += v0 + v1 + v2 + v3;
    }
    for (; e < end; ++e) acc += Y[(size_t)csr_src[e] * F + f];

    float v = acc * in_isqrt[d];
    out[(size_t)d * F + f] = v > 0.0f ? v : 0.0f;
}

extern "C" void kernel_launch(void* const* d_in, const int* in_sizes, int n_in,
                              void* d_out, int out_size, void* d_ws, size_t ws_size,
                              hipStream_t stream) {
    const float* h  = (const float*)d_in[0];
    const int*   ei = (const int*)d_in[1];
    const float* W1 = (const float*)d_in[2];
    const float* W2 = (const float*)d_in[3];
    const float* W3 = (const float*)d_in[4];
    float* out = (float*)d_out;

    // workspace layout
    char* p = (char*)d_ws;
    int* out_cnt    = (int*)p;                 p += N_NODES * sizeof(int);
    int* in_cnt     = (int*)p;                 p += N_NODES * sizeof(int);
    int* row_off    = (int*)p;                 p += (N_NODES + 1) * sizeof(int);
    int* cursor     = (int*)p;                 p += N_NODES * sizeof(int);
    int* bsums      = (int*)p;                 p += 256 * sizeof(int);
    int* csr_src    = (int*)p;                 p += N_EDGES * sizeof(int);
    float* out_isqrt = (float*)p;              p += N_NODES * sizeof(float);
    float* in_isqrt  = (float*)p;              p += N_NODES * sizeof(float);
    float* buf0      = (float*)p;              p += (size_t)N_NODES * HIDDEN * sizeof(float);
    float* buf1      = (float*)p;              p += (size_t)N_NODES * HIDDEN * sizeof(float);

    const int eb = (N_EDGES + 255) / 256;

    // ---- CSR build + scales (once, reused by all 3 layers) ----
    hipMemsetAsync(out_cnt, 0, 2 * N_NODES * sizeof(int), stream);
    hist_kernel<<<eb, 256, 0, stream>>>(ei, out_cnt, in_cnt);
    scales_kernel<<<NB_SCAN, 256, 0, stream>>>(out_cnt, in_cnt, out_isqrt, in_isqrt);
    scan1_kernel<<<NB_SCAN, 256, 0, stream>>>(in_cnt, row_off, bsums);
    scan2_kernel<<<1, 256, 0, stream>>>(bsums, NB_SCAN);
    scan3_kernel<<<NB_SCAN, 256, 0, stream>>>(row_off, bsums, cursor);
    fill_kernel<<<eb, 256, 0, stream>>>(ei, cursor, csr_src);

    const int gemm_blocks = (N_NODES + 31) / 32;

    // ---- layer 1 ----
    gemm_kernel<HIDDEN><<<gemm_blocks, 256, 0, stream>>>(h, W1, out_isqrt, buf0, N_NODES);
    agg_kernel<HIDDEN><<<N_NODES, HIDDEN, 0, stream>>>(row_off, csr_src, buf0, in_isqrt, buf1);

    // ---- layer 2 ----
    gemm_kernel<HIDDEN><<<gemm_blocks, 256, 0, stream>>>(buf1, W2, out_isqrt, buf0, N_NODES);
    agg_kernel<HIDDEN><<<N_NODES, HIDDEN, 0, stream>>>(row_off, csr_src, buf0, in_isqrt, buf1);

    // ---- layer 3 ----
    gemm_kernel<NUM_CLASS><<<gemm_blocks, 256, 0, stream>>>(buf1, W3, out_isqrt, buf0, N_NODES);
    agg_kernel<NUM_CLASS><<<N_NODES, NUM_CLASS, 0, stream>>>(row_off, csr_src, buf0, in_isqrt, out);
}

// Round 3
// 480.846 us; speedup vs baseline: 4.3207x; 1.5422x over previous
//
#include <hip/hip_runtime.h>

#define N_NODES 50000
#define N_EDGES 1600000
#define FEAT 128
#define HIDDEN 128
#define NUM_CLASS 64

#define NBUCK ((N_NODES + 255) / 256)   // 196 buckets of 256 dst nodes
#define BSTRIDE 16384                    // fixed bucket region (mean 8163, sigma 90 -> never overflows)
#define EPB 4096                         // edges per bucket-pass block

// ---------------- src-degree histogram (1 atomic/edge) ----------------
__global__ __launch_bounds__(256) void hist_src_kernel(const int* __restrict__ ei,
                                                       int* __restrict__ out_cnt) {
    int e = blockIdx.x * 256 + threadIdx.x;
    if (e < N_EDGES) atomicAdd(&out_cnt[ei[e]], 1);
}

__global__ __launch_bounds__(256) void scales_out_kernel(const int* __restrict__ out_cnt,
                                                         float* __restrict__ out_isqrt) {
    int i = blockIdx.x * 256 + threadIdx.x;
    if (i < N_NODES) {
        int c = out_cnt[i]; if (c < 1) c = 1;
        out_isqrt[i] = rsqrtf((float)c);
    }
}

__global__ void binit_kernel(int* __restrict__ bcur) {
    int b = threadIdx.x;
    if (b < NBUCK) bcur[b] = b * BSTRIDE;
}

// ---------------- pass 1: bin edges by dst>>8 into bucket regions ----------------
__global__ __launch_bounds__(256) void bucket_kernel(const int* __restrict__ ei,
                                                     int* __restrict__ bcur,
                                                     unsigned* __restrict__ bucket_buf) {
    __shared__ int cnt[NBUCK];
    __shared__ int gbase[NBUCK];
    __shared__ int rank[NBUCK];
    const int tid = threadIdx.x;
    for (int i = tid; i < NBUCK; i += 256) { cnt[i] = 0; rank[i] = 0; }
    __syncthreads();

    const int base = blockIdx.x * EPB;
    unsigned packed[16];
    int bk[16];
#pragma unroll
    for (int j = 0; j < 16; ++j) {
        int e = base + tid + j * 256;
        if (e < N_EDGES) {
            unsigned s = (unsigned)ei[e];
            unsigned d = (unsigned)ei[N_EDGES + e];
            bk[j] = (int)(d >> 8);
            packed[j] = s | ((d & 255u) << 16);
            atomicAdd(&cnt[bk[j]], 1);
        } else bk[j] = -1;
    }
    __syncthreads();
    for (int i = tid; i < NBUCK; i += 256)
        if (cnt[i] > 0) gbase[i] = atomicAdd(&bcur[i], cnt[i]);
    __syncthreads();
#pragma unroll
    for (int j = 0; j < 16; ++j)
        if (bk[j] >= 0) {
            int r = atomicAdd(&rank[bk[j]], 1);
            bucket_buf[gbase[bk[j]] + r] = packed[j];
        }
}

// ---------------- scan bucket totals -> csr_base; set row_off[N] ----------------
__global__ __launch_bounds__(256) void bscan_kernel(const int* __restrict__ bcur,
                                                    int* __restrict__ csr_base,
                                                    int* __restrict__ row_off) {
    __shared__ int tmp[256];
    int b = threadIdx.x;
    int v = (b < NBUCK) ? (bcur[b] - b * BSTRIDE) : 0;
    tmp[b] = v;
    __syncthreads();
    for (int off = 1; off < 256; off <<= 1) {
        int t = (b >= off) ? tmp[b - off] : 0;
        __syncthreads();
        tmp[b] += t;
        __syncthreads();
    }
    if (b < NBUCK) csr_base[b] = tmp[b] - v;   // exclusive
    if (b == 0) row_off[N_NODES] = N_EDGES;
}

// ---------------- pass 2: per-bucket counting sort; emits row_off + in_isqrt ----------------
__global__ __launch_bounds__(256) void csr_kernel(const int* __restrict__ bcur,
                                                  const int* __restrict__ csr_base,
                                                  const unsigned* __restrict__ bucket_buf,
                                                  int* __restrict__ csr_src,
                                                  int* __restrict__ row_off,
                                                  float* __restrict__ in_isqrt) {
    __shared__ int cnt[256];
    __shared__ int cur[256];
    __shared__ int tmp[256];
    const int b = blockIdx.x;
    const int j = threadIdx.x;
    const int ebeg = b * BSTRIDE;
    const int eend = bcur[b];

    cnt[j] = 0;
    __syncthreads();
    for (int e = ebeg + j; e < eend; e += 256)
        atomicAdd(&cnt[(bucket_buf[e] >> 16) & 255u], 1);
    __syncthreads();

    const int v = cnt[j];
    tmp[j] = v;
    __syncthreads();
    for (int off = 1; off < 256; off <<= 1) {
        int t = (j >= off) ? tmp[j - off] : 0;
        __syncthreads();
        tmp[j] += t;
        __syncthreads();
    }
    const int my_off = csr_base[b] + tmp[j] - v;
    cur[j] = my_off;
    const int node = (b << 8) + j;
    if (node < N_NODES) {
        row_off[node] = my_off;
        in_isqrt[node] = rsqrtf((float)(v > 0 ? v : 1));
    }
    __syncthreads();

    for (int e = ebeg + j; e < eend; e += 256) {
        unsigned p = bucket_buf[e];
        int pos = atomicAdd(&cur[(p >> 16) & 255u], 1);
        csr_src[pos] = (int)(p & 0xFFFFu);
    }
}

// ---------------- dense projection: Y[n][:] = scale[n] * (H[n][:] @ W) ----------------
template <int OUT>
__global__ __launch_bounds__(256) void gemm_kernel(const float* __restrict__ H,
                                                   const float* __restrict__ W,
                                                   const float* __restrict__ scale,
                                                   float* __restrict__ Y) {
    constexpr int TN = 32;
    constexpr int NCG = OUT / 4;       // float4 col groups: 32 / 16
    constexpr int NGRP = 256 / NCG;    // node groups: 8 / 16
    constexpr int NPT = TN / NGRP;     // nodes per thread: 4 / 2
    __shared__ float Hs[TN][FEAT];     // 16 KB
    __shared__ float4 Ws[FEAT * NCG];  // 64 KB (OUT=128) / 32 KB

    const int bn = blockIdx.x * TN;
    const int tid = threadIdx.x;

    for (int i = tid; i < FEAT * NCG; i += 256)
        Ws[i] = ((const float4*)W)[i];
    for (int i = tid; i < TN * FEAT / 4; i += 256) {
        int n = bn + (i * 4) / FEAT;
        float4 z = {0.f, 0.f, 0.f, 0.f};
        ((float4*)&Hs[0][0])[i] = (n < N_NODES) ? ((const float4*)H)[(size_t)bn * (FEAT / 4) + i] : z;
    }
    __syncthreads();

    const int cg = tid % NCG;
    const int ng = tid / NCG;

    float4 acc[NPT];
#pragma unroll
    for (int i = 0; i < NPT; ++i) acc[i] = {0.f, 0.f, 0.f, 0.f};

#pragma unroll 4
    for (int k = 0; k < FEAT; ++k) {
        const float4 w = Ws[k * NCG + cg];
#pragma unroll
        for (int i = 0; i < NPT; ++i) {
            const float a = Hs[ng * NPT + i][k];
            acc[i].x += a * w.x; acc[i].y += a * w.y;
            acc[i].z += a * w.z; acc[i].w += a * w.w;
        }
    }
#pragma unroll
    for (int i = 0; i < NPT; ++i) {
        const int gn = bn + ng * NPT + i;
        if (gn < N_NODES) {
            const float s = scale[gn];
            float4 r = {acc[i].x * s, acc[i].y * s, acc[i].z * s, acc[i].w * s};
            *(float4*)&Y[(size_t)gn * OUT + cg * 4] = r;
        }
    }
}

// ---------------- CSR gather-aggregate + in_isqrt scale + relu ----------------
// wave-per-dst; lane reads float4; EPW edges processed per load instruction.
template <int F>
__global__ __launch_bounds__(256) void agg_kernel(const int* __restrict__ row_off,
                                                  const int* __restrict__ csr_src,
                                                  const float* __restrict__ Y,
                                                  const float* __restrict__ in_isqrt,
                                                  float* __restrict__ out) {
    constexpr int NF4 = F / 4;          // lanes per edge: 32 / 16
    constexpr int EPW = 64 / NF4;       // edges per instr: 2 / 4
    const int wid = threadIdx.x >> 6;
    const int lane = threadIdx.x & 63;
    const int d = blockIdx.x * 4 + wid;
    if (d >= N_NODES) return;
    const int sub = lane / NF4;
    const int q = lane % NF4;
    const int beg = row_off[d];
    const int end = row_off[d + 1];

    float4 acc = {0.f, 0.f, 0.f, 0.f};
    int e = beg;
    for (; e + 4 * EPW <= end; e += 4 * EPW) {
        const int s0 = csr_src[e + 0 * EPW + sub];
        const int s1 = csr_src[e + 1 * EPW + sub];
        const int s2 = csr_src[e + 2 * EPW + sub];
        const int s3 = csr_src[e + 3 * EPW + sub];
        const float4 v0 = *(const float4*)(Y + (size_t)s0 * F + q * 4);
        const float4 v1 = *(const float4*)(Y + (size_t)s1 * F + q * 4);
        const float4 v2 = *(const float4*)(Y + (size_t)s2 * F + q * 4);
        const float4 v3 = *(const float4*)(Y + (size_t)s3 * F + q * 4);
        acc.x += v0.x + v1.x + v2.x + v3.x;
        acc.y += v0.y + v1.y + v2.y + v3.y;
        acc.z += v0.z + v1.z + v2.z + v3.z;
        acc.w += v0.w + v1.w + v2.w + v3.w;
    }
    for (; e + EPW <= end; e += EPW) {
        const int s = csr_src[e + sub];
        const float4 v = *(const float4*)(Y + (size_t)s * F + q * 4);
        acc.x += v.x; acc.y += v.y; acc.z += v.z; acc.w += v.w;
    }
    if (e < end && sub < end - e) {
        const int s = csr_src[e + sub];
        const float4 v = *(const float4*)(Y + (size_t)s * F + q * 4);
        acc.x += v.x; acc.y += v.y; acc.z += v.z; acc.w += v.w;
    }

    for (int m = NF4; m < 64; m <<= 1) {
        acc.x += __shfl_xor(acc.x, m, 64);
        acc.y += __shfl_xor(acc.y, m, 64);
        acc.z += __shfl_xor(acc.z, m, 64);
        acc.w += __shfl_xor(acc.w, m, 64);
    }

    if (lane < NF4) {
        const float isq = in_isqrt[d];
        float4 r;
        r.x = fmaxf(acc.x * isq, 0.f);
        r.y = fmaxf(acc.y * isq, 0.f);
        r.z = fmaxf(acc.z * isq, 0.f);
        r.w = fmaxf(acc.w * isq, 0.f);
        *(float4*)(out + (size_t)d * F + lane * 4) = r;
    }
}

extern "C" void kernel_launch(void* const* d_in, const int* in_sizes, int n_in,
                              void* d_out, int out_size, void* d_ws, size_t ws_size,
                              hipStream_t stream) {
    const float* h  = (const float*)d_in[0];
    const int*   ei = (const int*)d_in[1];
    const float* W1 = (const float*)d_in[2];
    const float* W2 = (const float*)d_in[3];
    const float* W3 = (const float*)d_in[4];
    float* out = (float*)d_out;

    // 256B-aligned bump allocator over d_ws
    char* p = (char*)d_ws;
    auto alloc = [&p](size_t bytes) {
        void* r = (void*)p;
        p += (bytes + 255) & ~(size_t)255;
        return r;
    };
    int*   out_cnt   = (int*)alloc(N_NODES * sizeof(int));
    int*   row_off   = (int*)alloc((N_NODES + 1) * sizeof(int));
    int*   bcur      = (int*)alloc(NBUCK * sizeof(int));
    int*   csr_base  = (int*)alloc(NBUCK * sizeof(int));
    int*   csr_src   = (int*)alloc((size_t)N_EDGES * sizeof(int));
    float* out_isqrt = (float*)alloc(N_NODES * sizeof(float));
    float* in_isqrt  = (float*)alloc(N_NODES * sizeof(float));
    float* buf0      = (float*)alloc((size_t)N_NODES * HIDDEN * sizeof(float));
    float* buf1      = (float*)alloc((size_t)N_NODES * HIDDEN * sizeof(float));
    // bucket_buf (NBUCK*BSTRIDE = 12.85 MB) aliases buf0 (25.6 MB): fully
    // consumed by csr_kernel before the first gemm writes buf0 (stream order).
    unsigned* bucket_buf = (unsigned*)buf0;

    const int eb = (N_EDGES + 255) / 256;

    // ---- graph preprocessing (once; reused by all 3 layers) ----
    hipMemsetAsync(out_cnt, 0, N_NODES * sizeof(int), stream);
    hist_src_kernel<<<eb, 256, 0, stream>>>(ei, out_cnt);
    scales_out_kernel<<<NBUCK, 256, 0, stream>>>(out_cnt, out_isqrt);
    binit_kernel<<<1, 256, 0, stream>>>(bcur);
    bucket_kernel<<<(N_EDGES + EPB - 1) / EPB, 256, 0, stream>>>(ei, bcur, bucket_buf);
    bscan_kernel<<<1, 256, 0, stream>>>(bcur, csr_base, row_off);
    csr_kernel<<<NBUCK, 256, 0, stream>>>(bcur, csr_base, bucket_buf, csr_src, row_off, in_isqrt);

    const int gemm_blocks = (N_NODES + 31) / 32;
    const int agg_blocks = (N_NODES + 3) / 4;

    // ---- layer 1 ----
    gemm_kernel<HIDDEN><<<gemm_blocks, 256, 0, stream>>>(h, W1, out_isqrt, buf0);
    agg_kernel<HIDDEN><<<agg_blocks, 256, 0, stream>>>(row_off, csr_src, buf0, in_isqrt, buf1);

    // ---- layer 2 ----
    gemm_kernel<HIDDEN><<<gemm_blocks, 256, 0, stream>>>(buf1, W2, out_isqrt, buf0);
    agg_kernel<HIDDEN><<<agg_blocks, 256, 0, stream>>>(row_off, csr_src, buf0, in_isqrt, buf1);

    // ---- layer 3 ----
    gemm_kernel<NUM_CLASS><<<gemm_blocks, 256, 0, stream>>>(buf1, W3, out_isqrt, buf0);
    agg_kernel<NUM_CLASS><<<agg_blocks, 256, 0, stream>>>(row_off, csr_src, buf0, in_isqrt, out);
}

// Round 4
// 450.622 us; speedup vs baseline: 4.6105x; 1.0671x over previous
//
#include <hip/hip_runtime.h>

#define N_NODES 50000
#define N_EDGES 1600000
#define FEAT 128
#define HIDDEN 128
#define NUM_CLASS 64

#define NBUCK 196        // ceil(50000/256) dst buckets
#define BSTRIDE 16384    // bucket region (mean 8163, sigma ~90)
#define EPB 4096         // edges per bucket-pass block
#define AGG_NBN 3125     // 50000/16 dst-blocks for agg (16 dst/block, exact)
#define GEMM_TN 64
#define GEMM_BLOCKS 782  // ceil(50000/64)

__global__ void binit_kernel(int* __restrict__ bcur) {
    int b = threadIdx.x;
    if (b < NBUCK) bcur[b] = b * BSTRIDE;
}

// ---- pass 1: bin edges by dst>>8 into bucket regions; also src-degree histogram ----
__global__ __launch_bounds__(256) void bucket_kernel(const int* __restrict__ ei,
                                                     int* __restrict__ bcur,
                                                     unsigned* __restrict__ bucket_buf,
                                                     int* __restrict__ out_cnt) {
    __shared__ int cnt[NBUCK];
    __shared__ int gbase[NBUCK];
    __shared__ int rank[NBUCK];
    const int tid = threadIdx.x;
    for (int i = tid; i < NBUCK; i += 256) { cnt[i] = 0; rank[i] = 0; }
    __syncthreads();

    const int base = blockIdx.x * EPB;
    unsigned packed[16];
    int bk[16];
#pragma unroll
    for (int j = 0; j < 16; ++j) {
        int e = base + tid + j * 256;
        if (e < N_EDGES) {
            unsigned s = (unsigned)ei[e];
            unsigned d = (unsigned)ei[N_EDGES + e];
            atomicAdd(&out_cnt[s], 1);
            bk[j] = (int)(d >> 8);
            packed[j] = s | ((d & 255u) << 16);
            atomicAdd(&cnt[bk[j]], 1);
        } else bk[j] = -1;
    }
    __syncthreads();
    for (int i = tid; i < NBUCK; i += 256)
        if (cnt[i] > 0) gbase[i] = atomicAdd(&bcur[i], cnt[i]);
    __syncthreads();
#pragma unroll
    for (int j = 0; j < 16; ++j)
        if (bk[j] >= 0) {
            int r = atomicAdd(&rank[bk[j]], 1);
            bucket_buf[gbase[bk[j]] + r] = packed[j];
        }
}

// ---- scan bucket totals -> csr_base ----
__global__ __launch_bounds__(256) void bscan_kernel(const int* __restrict__ bcur,
                                                    int* __restrict__ csr_base,
                                                    int* __restrict__ row_off) {
    __shared__ int tmp[256];
    int b = threadIdx.x;
    int v = (b < NBUCK) ? (bcur[b] - b * BSTRIDE) : 0;
    tmp[b] = v;
    __syncthreads();
    for (int off = 1; off < 256; off <<= 1) {
        int t = (b >= off) ? tmp[b - off] : 0;
        __syncthreads();
        tmp[b] += t;
        __syncthreads();
    }
    if (b < NBUCK) csr_base[b] = tmp[b] - v;
    if (b == 0) row_off[N_NODES] = N_EDGES;
}

// ---- pass 2: per-bucket counting sort -> csr (ushort src), row_off, in_isqrt ----
__global__ __launch_bounds__(256) void csr_kernel(const int* __restrict__ bcur,
                                                  const int* __restrict__ csr_base,
                                                  const unsigned* __restrict__ bucket_buf,
                                                  unsigned short* __restrict__ csr,
                                                  int* __restrict__ row_off,
                                                  float* __restrict__ in_isqrt) {
    __shared__ int cnt[256];
    __shared__ int cur[256];
    __shared__ int tmp[256];
    const int b = blockIdx.x;
    const int j = threadIdx.x;
    const int ebeg = b * BSTRIDE;
    const int eend = bcur[b];

    cnt[j] = 0;
    __syncthreads();
    for (int e = ebeg + j; e < eend; e += 256)
        atomicAdd(&cnt[(bucket_buf[e] >> 16) & 255u], 1);
    __syncthreads();

    const int v = cnt[j];
    tmp[j] = v;
    __syncthreads();
    for (int off = 1; off < 256; off <<= 1) {
        int t = (j >= off) ? tmp[j - off] : 0;
        __syncthreads();
        tmp[j] += t;
        __syncthreads();
    }
    const int my_off = csr_base[b] + tmp[j] - v;
    cur[j] = my_off;
    const int node = (b << 8) + j;
    if (node < N_NODES) {
        row_off[node] = my_off;
        in_isqrt[node] = rsqrtf((float)(v > 0 ? v : 1));
    }
    __syncthreads();

    for (int e = ebeg + j; e < eend; e += 256) {
        unsigned p = bucket_buf[e];
        int pos = atomicAdd(&cur[(p >> 16) & 255u], 1);
        csr[pos] = (unsigned short)(p & 0xFFFFu);
    }
}

// ---- dense projection: Ys[slice][n][16] = rsqrt(out_deg[n]) * (H[n][:] @ W) ----
template <int OUT>
__global__ __launch_bounds__(256) void gemm_kernel(const float* __restrict__ H,
                                                   const float* __restrict__ Wg,
                                                   const int* __restrict__ out_cnt,
                                                   float* __restrict__ Ys) {
    constexpr int NCG = OUT / 8;                      // 8-col groups: 16 / 8
    constexpr int RN = GEMM_TN * OUT / (256 * 8);     // nodes/thread: 4 / 2
    __shared__ float Hst[FEAT][GEMM_TN];              // transposed H tile, 32 KB

    const int tid = threadIdx.x;
    const int bn = blockIdx.x * GEMM_TN;

    // stage H transposed (lane n consecutive -> conflict-free ds_write)
    {
        const int n = tid & 63;
        const int kg = tid >> 6;                      // 0..3, 32 k's each
        const int gn = bn + n;
        if (gn < N_NODES) {
            const float4* hrow = (const float4*)(H + (size_t)gn * FEAT) + kg * 8;
#pragma unroll
            for (int jj = 0; jj < 8; ++jj) {
                float4 v = hrow[jj];
                const int k0 = kg * 32 + jj * 4;
                Hst[k0 + 0][n] = v.x;
                Hst[k0 + 1][n] = v.y;
                Hst[k0 + 2][n] = v.z;
                Hst[k0 + 3][n] = v.w;
            }
        } else {
#pragma unroll
            for (int jj = 0; jj < 8; ++jj) {
                const int k0 = kg * 32 + jj * 4;
                Hst[k0 + 0][n] = 0.f; Hst[k0 + 1][n] = 0.f;
                Hst[k0 + 2][n] = 0.f; Hst[k0 + 3][n] = 0.f;
            }
        }
    }
    __syncthreads();

    const int cq = tid & (NCG - 1);
    const int ng = tid / NCG;
    const float4* W4 = (const float4*)Wg;

    float4 acc[RN][2];
#pragma unroll
    for (int i = 0; i < RN; ++i) {
        acc[i][0] = {0.f, 0.f, 0.f, 0.f};
        acc[i][1] = {0.f, 0.f, 0.f, 0.f};
    }

#pragma unroll 4
    for (int k = 0; k < FEAT; ++k) {
        const float4 w0 = W4[k * (OUT / 4) + cq * 2];
        const float4 w1 = W4[k * (OUT / 4) + cq * 2 + 1];
        if constexpr (RN == 4) {
            const float4 a = *(const float4*)&Hst[k][ng * 4];
            acc[0][0].x += a.x * w0.x; acc[0][0].y += a.x * w0.y; acc[0][0].z += a.x * w0.z; acc[0][0].w += a.x * w0.w;
            acc[0][1].x += a.x * w1.x; acc[0][1].y += a.x * w1.y; acc[0][1].z += a.x * w1.z; acc[0][1].w += a.x * w1.w;
            acc[1][0].x += a.y * w0.x; acc[1][0].y += a.y * w0.y; acc[1][0].z += a.y * w0.z; acc[1][0].w += a.y * w0.w;
            acc[1][1].x += a.y * w1.x; acc[1][1].y += a.y * w1.y; acc[1][1].z += a.y * w1.z; acc[1][1].w += a.y * w1.w;
            acc[2][0].x += a.z * w0.x; acc[2][0].y += a.z * w0.y; acc[2][0].z += a.z * w0.z; acc[2][0].w += a.z * w0.w;
            acc[2][1].x += a.z * w1.x; acc[2][1].y += a.z * w1.y; acc[2][1].z += a.z * w1.z; acc[2][1].w += a.z * w1.w;
            acc[3][0].x += a.w * w0.x; acc[3][0].y += a.w * w0.y; acc[3][0].z += a.w * w0.z; acc[3][0].w += a.w * w0.w;
            acc[3][1].x += a.w * w1.x; acc[3][1].y += a.w * w1.y; acc[3][1].z += a.w * w1.z; acc[3][1].w += a.w * w1.w;
        } else {
            const float2 a = *(const float2*)&Hst[k][ng * 2];
            acc[0][0].x += a.x * w0.x; acc[0][0].y += a.x * w0.y; acc[0][0].z += a.x * w0.z; acc[0][0].w += a.x * w0.w;
            acc[0][1].x += a.x * w1.x; acc[0][1].y += a.x * w1.y; acc[0][1].z += a.x * w1.z; acc[0][1].w += a.x * w1.w;
            acc[1][0].x += a.y * w0.x; acc[1][0].y += a.y * w0.y; acc[1][0].z += a.y * w0.z; acc[1][0].w += a.y * w0.w;
            acc[1][1].x += a.y * w1.x; acc[1][1].y += a.y * w1.y; acc[1][1].z += a.y * w1.z; acc[1][1].w += a.y * w1.w;
        }
    }

#pragma unroll
    for (int i = 0; i < RN; ++i) {
        const int gn = bn + ng * RN + i;
        if (gn < N_NODES) {
            int c = out_cnt[gn];
            const float sc = rsqrtf((float)(c < 1 ? 1 : c));
#pragma unroll
            for (int pl = 0; pl < 2; ++pl) {
                const int col = cq * 8 + pl * 4;
                float4 r;
                r.x = acc[i][pl].x * sc; r.y = acc[i][pl].y * sc;
                r.z = acc[i][pl].z * sc; r.w = acc[i][pl].w * sc;
                *(float4*)(Ys + ((size_t)(col >> 4) * N_NODES + gn) * 16 + (col & 15)) = r;
            }
        }
    }
}

// ---- sliced CSR gather-aggregate + in_isqrt + relu ----
// block: slice s = bid & (NS-1) (XCD-pinned), 16 dsts; wave: 4 dsts x 4 edges x float4
template <int F>
__global__ __launch_bounds__(256) void agg_kernel(const int* __restrict__ row_off,
                                                  const unsigned short* __restrict__ csr,
                                                  const float* __restrict__ Ys,
                                                  const float* __restrict__ in_isqrt,
                                                  float* __restrict__ out) {
    constexpr int NS = F / 16;
    const int s  = blockIdx.x & (NS - 1);
    const int nb = blockIdx.x / NS;
    const int tid = threadIdx.x;
    const int lane = tid & 63;
    const int j = lane >> 4;           // dst sub 0..3
    const int esub = (lane >> 2) & 3;  // edge sub 0..3
    const int q = lane & 3;            // float4 quarter

    const int d = nb * 16 + (tid >> 6) * 4 + j;      // exact: 3125*16 = 50000
    const float* Yp = Ys + (size_t)s * (N_NODES * 16) + q * 4;

    const int end = row_off[d + 1];
    float4 acc = {0.f, 0.f, 0.f, 0.f};
    for (int e = row_off[d] + esub; e < end; e += 4) {
        const float4 v = *(const float4*)(Yp + (size_t)csr[e] * 16);
        acc.x += v.x; acc.y += v.y; acc.z += v.z; acc.w += v.w;
    }
#pragma unroll
    for (int m = 4; m <= 8; m <<= 1) {
        acc.x += __shfl_xor(acc.x, m, 64);
        acc.y += __shfl_xor(acc.y, m, 64);
        acc.z += __shfl_xor(acc.z, m, 64);
        acc.w += __shfl_xor(acc.w, m, 64);
    }
    if (esub == 0) {
        const float isq = in_isqrt[d];
        float4 r;
        r.x = fmaxf(acc.x * isq, 0.f);
        r.y = fmaxf(acc.y * isq, 0.f);
        r.z = fmaxf(acc.z * isq, 0.f);
        r.w = fmaxf(acc.w * isq, 0.f);
        *(float4*)(out + (size_t)d * F + s * 16 + q * 4) = r;
    }
}

extern "C" void kernel_launch(void* const* d_in, const int* in_sizes, int n_in,
                              void* d_out, int out_size, void* d_ws, size_t ws_size,
                              hipStream_t stream) {
    const float* h  = (const float*)d_in[0];
    const int*   ei = (const int*)d_in[1];
    const float* W1 = (const float*)d_in[2];
    const float* W2 = (const float*)d_in[3];
    const float* W3 = (const float*)d_in[4];
    float* out = (float*)d_out;

    char* p = (char*)d_ws;
    auto alloc = [&p](size_t bytes) {
        void* r = (void*)p;
        p += (bytes + 255) & ~(size_t)255;
        return r;
    };
    int*   out_cnt  = (int*)alloc(N_NODES * sizeof(int));
    int*   row_off  = (int*)alloc((N_NODES + 1) * sizeof(int));
    int*   bcur     = (int*)alloc(NBUCK * sizeof(int));
    int*   csr_base = (int*)alloc(NBUCK * sizeof(int));
    unsigned short* csr = (unsigned short*)alloc((size_t)N_EDGES * sizeof(unsigned short));
    float* in_isqrt = (float*)alloc(N_NODES * sizeof(float));
    float* buf0     = (float*)alloc((size_t)N_NODES * HIDDEN * sizeof(float));
    float* buf1     = (float*)alloc((size_t)N_NODES * HIDDEN * sizeof(float));
    // bucket_buf (12.85 MB) aliases buf0 (25.6 MB): fully consumed by csr_kernel
    // before the first gemm writes buf0 (stream order).
    unsigned* bucket_buf = (unsigned*)buf0;

    // ---- graph preprocessing (once; reused by all 3 layers) ----
    hipMemsetAsync(out_cnt, 0, N_NODES * sizeof(int), stream);
    binit_kernel<<<1, 256, 0, stream>>>(bcur);
    bucket_kernel<<<(N_EDGES + EPB - 1) / EPB, 256, 0, stream>>>(ei, bcur, bucket_buf, out_cnt);
    bscan_kernel<<<1, 256, 0, stream>>>(bcur, csr_base, row_off);
    csr_kernel<<<NBUCK, 256, 0, stream>>>(bcur, csr_base, bucket_buf, csr, row_off, in_isqrt);

    // ---- layer 1 ----
    gemm_kernel<HIDDEN><<<GEMM_BLOCKS, 256, 0, stream>>>(h, W1, out_cnt, buf0);
    agg_kernel<HIDDEN><<<8 * AGG_NBN, 256, 0, stream>>>(row_off, csr, buf0, in_isqrt, buf1);

    // ---- layer 2 ----
    gemm_kernel<HIDDEN><<<GEMM_BLOCKS, 256, 0, stream>>>(buf1, W2, out_cnt, buf0);
    agg_kernel<HIDDEN><<<8 * AGG_NBN, 256, 0, stream>>>(row_off, csr, buf0, in_isqrt, buf1);

    // ---- layer 3 ----
    gemm_kernel<NUM_CLASS><<<GEMM_BLOCKS, 256, 0, stream>>>(buf1, W3, out_cnt, buf0);
    agg_kernel<NUM_CLASS><<<4 * AGG_NBN, 256, 0, stream>>>(row_off, csr, buf0, in_isqrt, out);
}

// Round 5
// 334.048 us; speedup vs baseline: 6.2195x; 1.3490x over previous
//
#include <hip/hip_runtime.h>

#define N_NODES 50000
#define N_EDGES 1600000
#define FEAT 128
#define HIDDEN 128
#define NUM_CLASS 64

#define NBUCK 196        // ceil(50000/256) dst buckets
#define BSTRIDE 16384    // bucket region (mean 8163, sigma ~90)
#define EPB 4096         // edges per bucket-pass block
#define AGG_NBN 3125     // 50000/16 dst-blocks for agg (16 dst/block, exact)
#define GEMM_TN 64
#define GEMM_BLOCKS 782  // ceil(50000/64)

typedef _Float16 h8 __attribute__((ext_vector_type(8)));

__global__ void binit_kernel(int* __restrict__ bcur) {
    int b = threadIdx.x;
    if (b < NBUCK) bcur[b] = b * BSTRIDE;
}

// ---- pass 1: bin edges by dst>>8 into bucket regions; also src-degree histogram ----
__global__ __launch_bounds__(256) void bucket_kernel(const int* __restrict__ ei,
                                                     int* __restrict__ bcur,
                                                     unsigned* __restrict__ bucket_buf,
                                                     int* __restrict__ out_cnt) {
    __shared__ int cnt[NBUCK];
    __shared__ int gbase[NBUCK];
    __shared__ int rank[NBUCK];
    const int tid = threadIdx.x;
    for (int i = tid; i < NBUCK; i += 256) { cnt[i] = 0; rank[i] = 0; }
    __syncthreads();

    const int base = blockIdx.x * EPB;
    unsigned packed[16];
    int bk[16];
#pragma unroll
    for (int j = 0; j < 16; ++j) {
        int e = base + tid + j * 256;
        if (e < N_EDGES) {
            unsigned s = (unsigned)ei[e];
            unsigned d = (unsigned)ei[N_EDGES + e];
            atomicAdd(&out_cnt[s], 1);
            bk[j] = (int)(d >> 8);
            packed[j] = s | ((d & 255u) << 16);
            atomicAdd(&cnt[bk[j]], 1);
        } else bk[j] = -1;
    }
    __syncthreads();
    for (int i = tid; i < NBUCK; i += 256)
        if (cnt[i] > 0) gbase[i] = atomicAdd(&bcur[i], cnt[i]);
    __syncthreads();
#pragma unroll
    for (int j = 0; j < 16; ++j)
        if (bk[j] >= 0) {
            int r = atomicAdd(&rank[bk[j]], 1);
            bucket_buf[gbase[bk[j]] + r] = packed[j];
        }
}

// ---- scan bucket totals -> csr_base ----
__global__ __launch_bounds__(256) void bscan_kernel(const int* __restrict__ bcur,
                                                    int* __restrict__ csr_base,
                                                    int* __restrict__ row_off) {
    __shared__ int tmp[256];
    int b = threadIdx.x;
    int v = (b < NBUCK) ? (bcur[b] - b * BSTRIDE) : 0;
    tmp[b] = v;
    __syncthreads();
    for (int off = 1; off < 256; off <<= 1) {
        int t = (b >= off) ? tmp[b - off] : 0;
        __syncthreads();
        tmp[b] += t;
        __syncthreads();
    }
    if (b < NBUCK) csr_base[b] = tmp[b] - v;
    if (b == 0) row_off[N_NODES] = N_EDGES;
}

// ---- pass 2: per-bucket counting sort -> csr (ushort src), row_off, in_isqrt ----
__global__ __launch_bounds__(256) void csr_kernel(const int* __restrict__ bcur,
                                                  const int* __restrict__ csr_base,
                                                  const unsigned* __restrict__ bucket_buf,
                                                  unsigned short* __restrict__ csr,
                                                  int* __restrict__ row_off,
                                                  float* __restrict__ in_isqrt) {
    __shared__ int cnt[256];
    __shared__ int cur[256];
    __shared__ int tmp[256];
    const int b = blockIdx.x;
    const int j = threadIdx.x;
    const int ebeg = b * BSTRIDE;
    const int eend = bcur[b];

    cnt[j] = 0;
    __syncthreads();
    for (int e = ebeg + j; e < eend; e += 256)
        atomicAdd(&cnt[(bucket_buf[e] >> 16) & 255u], 1);
    __syncthreads();

    const int v = cnt[j];
    tmp[j] = v;
    __syncthreads();
    for (int off = 1; off < 256; off <<= 1) {
        int t = (j >= off) ? tmp[j - off] : 0;
        __syncthreads();
        tmp[j] += t;
        __syncthreads();
    }
    const int my_off = csr_base[b] + tmp[j] - v;
    cur[j] = my_off;
    const int node = (b << 8) + j;
    if (node < N_NODES) {
        row_off[node] = my_off;
        in_isqrt[node] = rsqrtf((float)(v > 0 ? v : 1));
    }
    __syncthreads();

    for (int e = ebeg + j; e < eend; e += 256) {
        unsigned p = bucket_buf[e];
        int pos = atomicAdd(&cur[(p >> 16) & 255u], 1);
        csr[pos] = (unsigned short)(p & 0xFFFFu);
    }
}

// ---- dense projection: Ys[slice][n][32] (fp16) = rsqrt(out_deg[n]) * (H[n][:] @ W) ----
template <int OUT>
__global__ __launch_bounds__(256) void gemm_kernel(const float* __restrict__ H,
                                                   const float* __restrict__ Wg,
                                                   const int* __restrict__ out_cnt,
                                                   _Float16* __restrict__ Ys) {
    constexpr int NCG = OUT / 8;                      // 8-col groups: 16 / 8
    constexpr int RN = GEMM_TN * OUT / (256 * 8);     // nodes/thread: 4 / 2
    __shared__ float Hst[FEAT][GEMM_TN];              // transposed H tile, 32 KB

    const int tid = threadIdx.x;
    const int bn = blockIdx.x * GEMM_TN;

    // stage H transposed (lane n consecutive -> conflict-free ds_write)
    {
        const int n = tid & 63;
        const int kg = tid >> 6;                      // 0..3, 32 k's each
        const int gn = bn + n;
        if (gn < N_NODES) {
            const float4* hrow = (const float4*)(H + (size_t)gn * FEAT) + kg * 8;
#pragma unroll
            for (int jj = 0; jj < 8; ++jj) {
                float4 v = hrow[jj];
                const int k0 = kg * 32 + jj * 4;
                Hst[k0 + 0][n] = v.x;
                Hst[k0 + 1][n] = v.y;
                Hst[k0 + 2][n] = v.z;
                Hst[k0 + 3][n] = v.w;
            }
        } else {
#pragma unroll
            for (int jj = 0; jj < 8; ++jj) {
                const int k0 = kg * 32 + jj * 4;
                Hst[k0 + 0][n] = 0.f; Hst[k0 + 1][n] = 0.f;
                Hst[k0 + 2][n] = 0.f; Hst[k0 + 3][n] = 0.f;
            }
        }
    }
    __syncthreads();

    const int cq = tid & (NCG - 1);
    const int ng = tid / NCG;
    const float4* W4 = (const float4*)Wg;

    float4 acc[RN][2];
#pragma unroll
    for (int i = 0; i < RN; ++i) {
        acc[i][0] = {0.f, 0.f, 0.f, 0.f};
        acc[i][1] = {0.f, 0.f, 0.f, 0.f};
    }

#pragma unroll 4
    for (int k = 0; k < FEAT; ++k) {
        const float4 w0 = W4[k * (OUT / 4) + cq * 2];
        const float4 w1 = W4[k * (OUT / 4) + cq * 2 + 1];
        if constexpr (RN == 4) {
            const float4 a = *(const float4*)&Hst[k][ng * 4];
            acc[0][0].x += a.x * w0.x; acc[0][0].y += a.x * w0.y; acc[0][0].z += a.x * w0.z; acc[0][0].w += a.x * w0.w;
            acc[0][1].x += a.x * w1.x; acc[0][1].y += a.x * w1.y; acc[0][1].z += a.x * w1.z; acc[0][1].w += a.x * w1.w;
            acc[1][0].x += a.y * w0.x; acc[1][0].y += a.y * w0.y; acc[1][0].z += a.y * w0.z; acc[1][0].w += a.y * w0.w;
            acc[1][1].x += a.y * w1.x; acc[1][1].y += a.y * w1.y; acc[1][1].z += a.y * w1.z; acc[1][1].w += a.y * w1.w;
            acc[2][0].x += a.z * w0.x; acc[2][0].y += a.z * w0.y; acc[2][0].z += a.z * w0.z; acc[2][0].w += a.z * w0.w;
            acc[2][1].x += a.z * w1.x; acc[2][1].y += a.z * w1.y; acc[2][1].z += a.z * w1.z; acc[2][1].w += a.z * w1.w;
            acc[3][0].x += a.w * w0.x; acc[3][0].y += a.w * w0.y; acc[3][0].z += a.w * w0.z; acc[3][0].w += a.w * w0.w;
            acc[3][1].x += a.w * w1.x; acc[3][1].y += a.w * w1.y; acc[3][1].z += a.w * w1.z; acc[3][1].w += a.w * w1.w;
        } else {
            const float2 a = *(const float2*)&Hst[k][ng * 2];
            acc[0][0].x += a.x * w0.x; acc[0][0].y += a.x * w0.y; acc[0][0].z += a.x * w0.z; acc[0][0].w += a.x * w0.w;
            acc[0][1].x += a.x * w1.x; acc[0][1].y += a.x * w1.y; acc[0][1].z += a.x * w1.z; acc[0][1].w += a.x * w1.w;
            acc[1][0].x += a.y * w0.x; acc[1][0].y += a.y * w0.y; acc[1][0].z += a.y * w0.z; acc[1][0].w += a.y * w0.w;
            acc[1][1].x += a.y * w1.x; acc[1][1].y += a.y * w1.y; acc[1][1].z += a.y * w1.z; acc[1][1].w += a.y * w1.w;
        }
    }

#pragma unroll
    for (int i = 0; i < RN; ++i) {
        const int gn = bn + ng * RN + i;
        if (gn < N_NODES) {
            int c = out_cnt[gn];
            const float sc = rsqrtf((float)(c < 1 ? 1 : c));
            const int sl = cq >> 2;                   // 32-feature slice
            const int off = (cq & 3) * 8;
            h8 r;
            r[0] = (_Float16)(acc[i][0].x * sc); r[1] = (_Float16)(acc[i][0].y * sc);
            r[2] = (_Float16)(acc[i][0].z * sc); r[3] = (_Float16)(acc[i][0].w * sc);
            r[4] = (_Float16)(acc[i][1].x * sc); r[5] = (_Float16)(acc[i][1].y * sc);
            r[6] = (_Float16)(acc[i][1].z * sc); r[7] = (_Float16)(acc[i][1].w * sc);
            *(h8*)(Ys + ((size_t)sl * N_NODES + gn) * 32 + off) = r;
        }
    }
}

// ---- sliced CSR gather-aggregate (fp16 rows) + in_isqrt + relu -> fp32 ----
// block: slice s = bid & (NS-1) (XCD-pinned), 16 dsts; wave: 4 dsts x 4 edges x 4 quarters
template <int F>
__global__ __launch_bounds__(256) void agg_kernel(const int* __restrict__ row_off,
                                                  const unsigned short* __restrict__ csr,
                                                  const _Float16* __restrict__ Ys,
                                                  const float* __restrict__ in_isqrt,
                                                  float* __restrict__ out) {
    constexpr int NS = F / 32;               // slices: 4 (F=128) / 2 (F=64)
    const int s  = blockIdx.x & (NS - 1);
    const int nb = blockIdx.x / NS;
    const int tid = threadIdx.x;
    const int lane = tid & 63;
    const int j = lane >> 4;                 // dst sub 0..3
    const int esub = (lane >> 2) & 3;        // edge sub 0..3
    const int q = lane & 3;                  // 8-feature quarter of the 32-slice

    const int d = nb * 16 + (tid >> 6) * 4 + j;          // exact: 3125*16 = 50000
    const _Float16* Yp = Ys + (size_t)s * (N_NODES * 32) + q * 8;

    const int end = row_off[d + 1];
    float a0 = 0.f, a1 = 0.f, a2 = 0.f, a3 = 0.f, a4 = 0.f, a5 = 0.f, a6 = 0.f, a7 = 0.f;

    int e = row_off[d] + esub;
    for (; e + 4 < end; e += 8) {            // 2-deep: cover idx->gather latency
        const int i0 = csr[e];
        const int i1 = csr[e + 4];
        const h8 v0 = *(const h8*)(Yp + (size_t)i0 * 32);
        const h8 v1 = *(const h8*)(Yp + (size_t)i1 * 32);
        a0 += (float)v0[0] + (float)v1[0];
        a1 += (float)v0[1] + (float)v1[1];
        a2 += (float)v0[2] + (float)v1[2];
        a3 += (float)v0[3] + (float)v1[3];
        a4 += (float)v0[4] + (float)v1[4];
        a5 += (float)v0[5] + (float)v1[5];
        a6 += (float)v0[6] + (float)v1[6];
        a7 += (float)v0[7] + (float)v1[7];
    }
    if (e < end) {
        const int i0 = csr[e];
        const h8 v0 = *(const h8*)(Yp + (size_t)i0 * 32);
        a0 += (float)v0[0]; a1 += (float)v0[1]; a2 += (float)v0[2]; a3 += (float)v0[3];
        a4 += (float)v0[4]; a5 += (float)v0[5]; a6 += (float)v0[6]; a7 += (float)v0[7];
    }

    // reduce over esub (lanes differing in bits 2,3)
    a0 += __shfl_xor(a0, 4, 64); a0 += __shfl_xor(a0, 8, 64);
    a1 += __shfl_xor(a1, 4, 64); a1 += __shfl_xor(a1, 8, 64);
    a2 += __shfl_xor(a2, 4, 64); a2 += __shfl_xor(a2, 8, 64);
    a3 += __shfl_xor(a3, 4, 64); a3 += __shfl_xor(a3, 8, 64);
    a4 += __shfl_xor(a4, 4, 64); a4 += __shfl_xor(a4, 8, 64);
    a5 += __shfl_xor(a5, 4, 64); a5 += __shfl_xor(a5, 8, 64);
    a6 += __shfl_xor(a6, 4, 64); a6 += __shfl_xor(a6, 8, 64);
    a7 += __shfl_xor(a7, 4, 64); a7 += __shfl_xor(a7, 8, 64);

    if (esub == 0) {
        const float isq = in_isqrt[d];
        float4 r0, r1;
        r0.x = fmaxf(a0 * isq, 0.f); r0.y = fmaxf(a1 * isq, 0.f);
        r0.z = fmaxf(a2 * isq, 0.f); r0.w = fmaxf(a3 * isq, 0.f);
        r1.x = fmaxf(a4 * isq, 0.f); r1.y = fmaxf(a5 * isq, 0.f);
        r1.z = fmaxf(a6 * isq, 0.f); r1.w = fmaxf(a7 * isq, 0.f);
        float* op = out + (size_t)d * F + s * 32 + q * 8;
        *(float4*)op = r0;
        *(float4*)(op + 4) = r1;
    }
}

extern "C" void kernel_launch(void* const* d_in, const int* in_sizes, int n_in,
                              void* d_out, int out_size, void* d_ws, size_t ws_size,
                              hipStream_t stream) {
    const float* h  = (const float*)d_in[0];
    const int*   ei = (const int*)d_in[1];
    const float* W1 = (const float*)d_in[2];
    const float* W2 = (const float*)d_in[3];
    const float* W3 = (const float*)d_in[4];
    float* out = (float*)d_out;

    char* p = (char*)d_ws;
    auto alloc = [&p](size_t bytes) {
        void* r = (void*)p;
        p += (bytes + 255) & ~(size_t)255;
        return r;
    };
    int*   out_cnt  = (int*)alloc(N_NODES * sizeof(int));
    int*   row_off  = (int*)alloc((N_NODES + 1) * sizeof(int));
    int*   bcur     = (int*)alloc(NBUCK * sizeof(int));
    int*   csr_base = (int*)alloc(NBUCK * sizeof(int));
    unsigned short* csr = (unsigned short*)alloc((size_t)N_EDGES * sizeof(unsigned short));
    float* in_isqrt = (float*)alloc(N_NODES * sizeof(float));
    _Float16* Ys    = (_Float16*)alloc((size_t)N_NODES * HIDDEN * sizeof(_Float16));
    float* bufA     = (float*)alloc((size_t)N_NODES * HIDDEN * sizeof(float));
    float* bufB     = (float*)alloc((size_t)N_NODES * HIDDEN * sizeof(float));
    // bucket_buf (12.85 MB) aliases bufA (25.6 MB): fully consumed by csr_kernel
    // before layer-1 agg writes bufA (stream order).
    unsigned* bucket_buf = (unsigned*)bufA;

    // ---- graph preprocessing (once; reused by all 3 layers) ----
    hipMemsetAsync(out_cnt, 0, N_NODES * sizeof(int), stream);
    binit_kernel<<<1, 256, 0, stream>>>(bcur);
    bucket_kernel<<<(N_EDGES + EPB - 1) / EPB, 256, 0, stream>>>(ei, bcur, bucket_buf, out_cnt);
    bscan_kernel<<<1, 256, 0, stream>>>(bcur, csr_base, row_off);
    csr_kernel<<<NBUCK, 256, 0, stream>>>(bcur, csr_base, bucket_buf, csr, row_off, in_isqrt);

    // ---- layer 1 ----
    gemm_kernel<HIDDEN><<<GEMM_BLOCKS, 256, 0, stream>>>(h, W1, out_cnt, Ys);
    agg_kernel<HIDDEN><<<4 * AGG_NBN, 256, 0, stream>>>(row_off, csr, Ys, in_isqrt, bufA);

    // ---- layer 2 ----
    gemm_kernel<HIDDEN><<<GEMM_BLOCKS, 256, 0, stream>>>(bufA, W2, out_cnt, Ys);
    agg_kernel<HIDDEN><<<4 * AGG_NBN, 256, 0, stream>>>(row_off, csr, Ys, in_isqrt, bufB);

    // ---- layer 3 ----
    gemm_kernel<NUM_CLASS><<<GEMM_BLOCKS, 256, 0, stream>>>(bufB, W3, out_cnt, Ys);
    agg_kernel<NUM_CLASS><<<2 * AGG_NBN, 256, 0, stream>>>(row_off, csr, Ys, in_isqrt, out);
}